// Round 8
// baseline (187.924 us; speedup 1.0000x reference)
//
#include <hip/hip_runtime.h>
#include <hip/hip_bf16.h>
#include <math.h>

#define B_   16
#define L_   1024
#define F_   64
#define D_   256
#define S_   2
#define N_   16
#define H_   32
#define EPS_ 1e-5f
#define BL_  (B_*L_)
#define NCH_ 8          // t-chunks for the parallel scan
#define TC_  (L_/NCH_)  // 128 timesteps per chunk
#define SUB_ 64         // timesteps per sub-chunk
#define TSTR_ 68        // scan tile stride (floats); 272B rows, 16B aligned
#define LOG2E_ 1.44269504088896340736f
#define XBLK_ (BL_*F_/1024)   // 1024 xsplit blocks

typedef __attribute__((ext_vector_type(8))) short  bf16x8;
typedef __attribute__((ext_vector_type(4))) float  f32x4;
typedef __attribute__((ext_vector_type(2))) float  f32x2;

typedef const __attribute__((address_space(1))) void* gas_ptr;
typedef __attribute__((address_space(3))) void*       las_ptr;

#if defined(__has_builtin)
# if __has_builtin(__builtin_amdgcn_exp2f)
#  define EXP2(x) __builtin_amdgcn_exp2f(x)
#  define ASCALE_ LOG2E_
# endif
#endif
#ifndef EXP2
# define EXP2(x) __expf(x)
# define ASCALE_ 1.0f
#endif

__device__ inline void async_copy16(const void* g, void* l) {
    __builtin_amdgcn_global_load_lds((gas_ptr)g, (las_ptr)l, 16, 0, 0);
}

__device__ inline unsigned short f2bf_rne(float x) {
    union { float f; unsigned u; } v; v.f = x;
    unsigned r = v.u + 0x7fff + ((v.u >> 16) & 1);
    return (unsigned short)(r >> 16);
}
__device__ inline float bf2f(unsigned short h) {
    union { float f; unsigned u; } v; v.u = ((unsigned)h) << 16;
    return v.f;
}

// ---------------------------------------------------------------------------
// Kernel 1: combined prep.
//  blocks [0, XBLK_):        split x into bf16 hi/lo (4 elems/thread)
//  blocks [XBLK_, +256):     Weff cols (4 jobs x 64 thr): Win @ W{d,tau} col
//  blocks [XBLK_+256, +64):  WinT rows (4 jobs)
//  blocks [XBLK_+320, +8):   WBe cols  (4 jobs)
// ---------------------------------------------------------------------------
__global__ __launch_bounds__(256) void k_prep(const float* __restrict__ x,
                                              const float* __restrict__ Win,
                                              const float* __restrict__ bin,
                                              const float* __restrict__ Wd,
                                              const float* __restrict__ bd,
                                              const float* __restrict__ Wt,
                                              const float* __restrict__ WB,
                                              unsigned short* __restrict__ x_hi,
                                              unsigned short* __restrict__ x_lo,
                                              unsigned short* __restrict__ Weff_hi,
                                              unsigned short* __restrict__ Weff_lo,
                                              float* __restrict__ bias_eff,
                                              unsigned short* __restrict__ WinT_hi,
                                              unsigned short* __restrict__ WinT_lo,
                                              unsigned short* __restrict__ WBe_hi,
                                              unsigned short* __restrict__ WBe_lo,
                                              float* __restrict__ bbias)
{
    const int blk = blockIdx.x;
    const int tid = threadIdx.x;

    if (blk < XBLK_) {
        const int i = (blk * 256 + tid) * 4;
        float4 v = *(const float4*)(x + i);
        ushort4 h4, l4;
        unsigned short hh;
        hh = f2bf_rne(v.x); h4.x = hh; l4.x = f2bf_rne(v.x - bf2f(hh));
        hh = f2bf_rne(v.y); h4.y = hh; l4.y = f2bf_rne(v.y - bf2f(hh));
        hh = f2bf_rne(v.z); h4.z = hh; l4.z = f2bf_rne(v.z - bf2f(hh));
        hh = f2bf_rne(v.w); h4.w = hh; l4.w = f2bf_rne(v.w - bf2f(hh));
        *(ushort4*)(x_hi + i) = h4;
        *(ushort4*)(x_lo + i) = l4;
        return;
    }

    const int job4 = blk - XBLK_;
    const int j    = tid >> 6;          // sub-job 0..3
    const int f    = tid & 63;
    const int job  = job4 * 4 + j;      // 0..1311

    __shared__ float col[4][D_];

    if (job < 1024) {                   // Weff: s = job>>9, n = job&511
        const int s = job >> 9, n = job & 511;
        const float* W = (n < 256) ? (Wd + (size_t)s * D_ * D_) : (Wt + (size_t)s * D_ * D_);
        const int e = n & 255;
        for (int d = f; d < D_; d += 64) col[j][d] = W[(size_t)d * D_ + e];
        __syncthreads();
        float a = 0.f;
        for (int d = 0; d < D_; ++d) a += Win[(size_t)f * D_ + d] * col[j][d];
        unsigned short hi = f2bf_rne(a);
        size_t o = ((size_t)s * 512 + n) * F_ + f;
        Weff_hi[o] = hi;
        Weff_lo[o] = f2bf_rne(a - bf2f(hi));
        if (f == 0) {
            float bb = 0.f;
            for (int d = 0; d < D_; ++d) bb += bin[d] * col[j][d];
            if (n < 256) bb += bd[s * D_ + e];
            bias_eff[s * 512 + n] = bb;
        }
    } else if (job < 1024 + D_) {       // WinT
        const int d = job - 1024;
        float v = Win[(size_t)f * D_ + d];
        unsigned short hi = f2bf_rne(v);
        size_t o = (size_t)d * F_ + f;
        WinT_hi[o] = hi;
        WinT_lo[o] = f2bf_rne(v - bf2f(hi));
    } else {                            // WBe
        const int idx = job - (1024 + D_);
        const int s = idx >> 4, n = idx & 15;
        const float* wb = WB + (size_t)s * D_ * N_;
        float a = 0.f;
        for (int d = 0; d < D_; ++d) a += Win[(size_t)f * D_ + d] * wb[(size_t)d * N_ + n];
        unsigned short hi = f2bf_rne(a);
        size_t o = ((size_t)s * N_ + n) * F_ + f;
        WBe_hi[o] = hi;
        WBe_lo[o] = f2bf_rne(a - bf2f(hi));
        if (f == 0) {
            float bb = 0.f;
            for (int d = 0; d < D_; ++d) bb += bin[d] * wb[(size_t)d * N_ + n];
            bbias[s * N_ + n] = bb;
        }
    }
}

// ---------------------------------------------------------------------------
// Kernel 2: FUSED gemm + activation + scan. One block per (s, b, d-tile,
// t-chunk of 128). A-fragments direct global->VGPR (prefetched); W strip in
// LDS (staged once). Scan: 4 t/iter, b128 tile reads, raw v_exp, packed f32.
// ---------------------------------------------------------------------------
__global__ __launch_bounds__(256) void k_fused_scan(
        const unsigned short* __restrict__ x_hi,
        const unsigned short* __restrict__ x_lo,
        const unsigned short* __restrict__ Weff_hi,
        const unsigned short* __restrict__ Weff_lo,
        const unsigned short* __restrict__ WinT_hi,
        const unsigned short* __restrict__ WinT_lo,
        const unsigned short* __restrict__ WBe_hi,
        const unsigned short* __restrict__ WBe_lo,
        const float* __restrict__ bias_eff,
        const float* __restrict__ bin,
        const float* __restrict__ bbias,
        const float* __restrict__ A_log,
        float* __restrict__ part,
        float* __restrict__ csum)
{
    const int dtile = blockIdx.x >> 3;
    const int c     = blockIdx.x & 7;
    const int b     = blockIdx.y;
    const int s     = blockIdx.z;
    const int d0    = dtile * 16;
    const int tid   = threadIdx.x;
    const int wid   = tid >> 6;
    const int lane  = tid & 63;
    const int l15   = lane & 15;
    const int quad  = lane >> 4;
    const int dl    = tid & 15;   // scan-phase: d within tile
    const int nl    = tid >> 4;   // scan-phase: n

    __shared__ unsigned short Wh[64 * F_];  // [col][f]: 0-15 d,16-31 tau,32-47 Win,48-63 WB
    __shared__ unsigned short Wl[64 * F_];
    __shared__ float sdl[16][TSTR_];        // [d][t] delta
    __shared__ float sq [16][TSTR_];        // [d][t] delta*h
    __shared__ float sb [16][TSTR_];        // [n][t] Bm

    const int r8 = lane >> 3;
    const int c8 = lane & 7;

    // ---- stage W strip once (wave wid = col group wid)
    #pragma unroll
    for (int call = 0; call < 2; ++call) {
        const int rr = call * 8 + r8;
        const int ar = wid * 16 + rr;
        const int lc = (c8 - ar) & 7;
        const unsigned short *gh, *gl;
        if (wid == 0)      { size_t o = ((size_t)s * 512 + d0 + rr) * F_ + lc * 8;       gh = Weff_hi + o; gl = Weff_lo + o; }
        else if (wid == 1) { size_t o = ((size_t)s * 512 + 256 + d0 + rr) * F_ + lc * 8; gh = Weff_hi + o; gl = Weff_lo + o; }
        else if (wid == 2) { size_t o = ((size_t)(d0 + rr)) * F_ + lc * 8;               gh = WinT_hi + o; gl = WinT_lo + o; }
        else               { size_t o = ((size_t)s * N_ + rr) * F_ + lc * 8;             gh = WBe_hi + o;  gl = WBe_lo + o; }
        async_copy16(gh, &Wh[(wid * 16 + call * 8) * F_]);
        async_copy16(gl, &Wl[(wid * 16 + call * 8) * F_]);
    }

    // per-lane constants
    const float bias_d = bias_eff[s * 512 + d0 + l15];
    const float bias_t = bias_eff[s * 512 + 256 + d0 + l15];
    const float bin_v  = bin[d0 + l15];
    const float bb_v   = bbias[s * N_ + l15];
    const float A2 = -__expf(A_log[((size_t)s * D_ + d0 + dl) * N_ + nl]) * ASCALE_;

    f32x2 st01 = {0.f, 0.f};
    f32x2 st23 = {0.f, 0.f};
    float As = 0.f;    // A2 * suffix-sum of delta

    const int qoff = quad * 8;
    const int nsc  = TC_ / SUB_;

    // preload A-fragments for first (highest) sub-chunk
    bf16x8 fah0, fah1, fal0, fal1;
    {
        const size_t rowb = ((size_t)b * L_ + c * TC_ + (nsc - 1) * SUB_ + wid * 16 + l15) * F_;
        fah0 = *(const bf16x8*)(x_hi + rowb + qoff);
        fah1 = *(const bf16x8*)(x_hi + rowb + 32 + qoff);
        fal0 = *(const bf16x8*)(x_lo + rowb + qoff);
        fal1 = *(const bf16x8*)(x_lo + rowb + 32 + qoff);
    }
    __syncthreads();   // W staged (drains the global_load_lds too)

    for (int sc = nsc - 1; sc >= 0; --sc) {
        // ---- MFMA: this wave's 16 t-rows x 4 col groups, K=64
        f32x4 acc[4];
        #pragma unroll
        for (int g = 0; g < 4; ++g) acc[g] = (f32x4){0.f, 0.f, 0.f, 0.f};
        #pragma unroll
        for (int ks = 0; ks < 2; ++ks) {
            bf16x8 ah = ks ? fah1 : fah0;
            bf16x8 al = ks ? fal1 : fal0;
            #pragma unroll
            for (int g = 0; g < 4; ++g) {
                const int brow = g * 16 + l15;
                const int pcB  = ((ks * 4 + quad) + brow) & 7;
                bf16x8 bh = *(const bf16x8*)&Wh[brow * F_ + pcB * 8];
                bf16x8 bl = *(const bf16x8*)&Wl[brow * F_ + pcB * 8];
                acc[g] = __builtin_amdgcn_mfma_f32_16x16x32_bf16(ah, bh, acc[g], 0, 0, 0);
                acc[g] = __builtin_amdgcn_mfma_f32_16x16x32_bf16(ah, bl, acc[g], 0, 0, 0);
                acc[g] = __builtin_amdgcn_mfma_f32_16x16x32_bf16(al, bh, acc[g], 0, 0, 0);
            }
        }

        // ---- prefetch next sub-chunk's A-fragments (completes under scan)
        bf16x8 nah0, nah1, nal0, nal1;
        const bool more = (sc > 0);
        if (more) {
            const size_t rowb = ((size_t)b * L_ + c * TC_ + (sc - 1) * SUB_ + wid * 16 + l15) * F_;
            nah0 = *(const bf16x8*)(x_hi + rowb + qoff);
            nah1 = *(const bf16x8*)(x_hi + rowb + 32 + qoff);
            nal0 = *(const bf16x8*)(x_lo + rowb + qoff);
            nal1 = *(const bf16x8*)(x_lo + rowb + 32 + qoff);
        }

        __syncthreads();   // previous scan reads done before tile overwrite

        // ---- epilogue: C layout col=l15, row=quad*4+r -> transposed tiles
        {
            f32x4 wd_, wq_, wb_;
            #pragma unroll
            for (int r = 0; r < 4; ++r) {
                const float pd  = acc[0][r] + bias_d;
                const float sp  = fmaxf(pd, 0.f) + __logf(1.f + __expf(-fabsf(pd)));
                const float sg  = 1.f / (1.f + __expf(-(acc[1][r] + bias_t)));
                const float dlt = sp * sg;
                const float hv  = acc[2][r] + bin_v;
                wd_[r] = dlt;
                wq_[r] = dlt * hv;
                wb_[r] = acc[3][r] + bb_v;
            }
            const int tcol = wid * 16 + quad * 4;
            *(f32x4*)&sdl[l15][tcol] = wd_;
            *(f32x4*)&sq [l15][tcol] = wq_;
            *(f32x4*)&sb [l15][tcol] = wb_;
        }
        __syncthreads();

        // ---- backward suffix scan, 4 timesteps per iteration
        #pragma unroll 4
        for (int tt = SUB_ - 4; tt >= 0; tt -= 4) {
            f32x4 dp = *(const f32x4*)&sdl[dl][tt];
            f32x4 qp = *(const f32x4*)&sq [dl][tt];
            f32x4 bp = *(const f32x4*)&sb [nl][tt];
            const float a2v = fmaf(A2, dp.w, As);
            const float a1v = fmaf(A2, dp.z, a2v);
            const float a0v = fmaf(A2, dp.y, a1v);
            f32x2 e01, e23;
            e23.y = EXP2(As);
            e23.x = EXP2(a2v);
            e01.y = EXP2(a1v);
            e01.x = EXP2(a0v);
            f32x2 q01 = {qp.x, qp.y}, q23 = {qp.z, qp.w};
            f32x2 b01 = {bp.x, bp.y}, b23 = {bp.z, bp.w};
            st01 = q01 * b01 * e01 + st01;
            st23 = q23 * b23 * e23 + st23;
            As = fmaf(A2, dp.x, a0v);
        }

        if (more) { fah0 = nah0; fah1 = nah1; fal0 = nal0; fal1 = nal1; }
    }

    const size_t pb = ((size_t)s * B_ + b) * NCH_ + c;
    part[(pb * D_ + d0 + dl) * N_ + nl] = (st01.x + st01.y) + (st23.x + st23.y);
    if (nl == 0)
        csum[pb * D_ + d0 + dl] = As / A2;
}

// ---------------------------------------------------------------------------
// Kernel 3: final readout with inline chunk-combine. One block per b.
// ---------------------------------------------------------------------------
__global__ __launch_bounds__(256) void k_final(const float* __restrict__ x,
                                               const float* __restrict__ Win,
                                               const float* __restrict__ bin,
                                               const float* __restrict__ part,
                                               const float* __restrict__ csum,
                                               const float* __restrict__ A_log,
                                               const float* __restrict__ WC,
                                               const float* __restrict__ Dp,
                                               const float* __restrict__ Wout,
                                               const float* __restrict__ ln_g,
                                               const float* __restrict__ ln_b,
                                               const float* __restrict__ W1,
                                               const float* __restrict__ b1,
                                               const float* __restrict__ W2,
                                               const float* __restrict__ b2,
                                               float* __restrict__ out)
{
    const int b   = blockIdx.x;
    const int tid = threadIdx.x;

    __shared__ float xr[F_];
    __shared__ float hl[D_];
    __shared__ float cm[S_][N_];
    __shared__ float ys[S_][D_];
    __shared__ float zv[D_];
    __shared__ float red1[256];
    __shared__ float red2[256];
    __shared__ float r1[H_];

    if (tid < F_) xr[tid] = x[((size_t)b * L_ + (L_ - 1)) * F_ + tid];
    __syncthreads();

    {   // h_last[d] = x_last . Win[:,d] + bin[d]
        float a = bin[tid];
        for (int f = 0; f < F_; ++f) a += xr[f] * Win[(size_t)f * D_ + tid];
        hl[tid] = a;
    }
    __syncthreads();

    if (tid < S_ * N_) {
        int s = tid >> 4, n = tid & 15;
        float a = 0.f;
        for (int d = 0; d < D_; ++d) a += hl[d] * WC[((size_t)s * D_ + d) * N_ + n];
        cm[s][n] = a;
    }
    __syncthreads();

    // ys[s][d] = sum_n cm[s][n] * state[d][n] + h_last[d]*Dp ; states combined
    // inline from the NCH_ chunk partials.
    for (int s = 0; s < S_; ++s) {
        const float* al = A_log + ((size_t)s * D_ + tid) * N_;
        float a2v[N_];
        #pragma unroll
        for (int n = 0; n < N_; ++n) a2v[n] = -__expf(al[n]);
        const size_t cbase = ((size_t)s * B_ + b) * NCH_;
        float cs[NCH_];
        #pragma unroll
        for (int c = 0; c < NCH_; ++c) cs[c] = csum[(cbase + c) * D_ + tid];
        float acc = 0.f;
        float tail = 0.f;
        #pragma unroll
        for (int c = NCH_ - 1; c >= 0; --c) {
            const float* pp = part + ((cbase + c) * D_ + tid) * N_;
            #pragma unroll
            for (int n = 0; n < N_; ++n)
                acc += cm[s][n] * __expf(a2v[n] * tail) * pp[n];
            tail += cs[c];
        }
        ys[s][tid] = acc + hl[tid] * Dp[s * D_ + tid];
    }
    __syncthreads();

    float v;
    {
        float a = 0.f;
        for (int s = 0; s < S_; ++s) {
            const float* wo = Wout + (size_t)s * D_ * D_;
            for (int d = 0; d < D_; ++d) a += ys[s][d] * wo[(size_t)d * D_ + tid];
        }
        v = a * (1.f / S_);
    }

    red1[tid] = v;
    red2[tid] = v * v;
    __syncthreads();
    for (int off = 128; off > 0; off >>= 1) {
        if (tid < off) { red1[tid] += red1[tid + off]; red2[tid] += red2[tid + off]; }
        __syncthreads();
    }
    const float mu  = red1[0] * (1.f / D_);
    const float var = red2[0] * (1.f / D_) - mu * mu;
    const float z = (v - mu) * rsqrtf(var + EPS_) * ln_g[tid] + ln_b[tid];
    zv[tid] = z;
    __syncthreads();

    if (tid < H_) {
        float a = b1[tid];
        for (int e = 0; e < D_; ++e) a += zv[e] * W1[(size_t)e * H_ + tid];
        r1[tid] = fmaxf(a, 0.f);
    }
    __syncthreads();
    if (tid == 0) {
        float a = b2[0];
        for (int j = 0; j < H_; ++j) a += r1[j] * W2[j];
        out[b] = a;
    }
}

// ---------------------------------------------------------------------------
extern "C" void kernel_launch(void* const* d_in, const int* in_sizes, int n_in,
                              void* d_out, int out_size, void* d_ws, size_t ws_size,
                              hipStream_t stream)
{
    const float* x     = (const float*)d_in[0];
    const float* Win   = (const float*)d_in[1];
    const float* bin   = (const float*)d_in[2];
    const float* Wd    = (const float*)d_in[3];
    const float* bd    = (const float*)d_in[4];
    const float* WB    = (const float*)d_in[5];
    const float* WC    = (const float*)d_in[6];
    const float* Wtau  = (const float*)d_in[7];
    const float* A_log = (const float*)d_in[8];
    const float* Dp    = (const float*)d_in[9];
    const float* Wout  = (const float*)d_in[10];
    const float* ln_g  = (const float*)d_in[11];
    const float* ln_b  = (const float*)d_in[12];
    const float* W1    = (const float*)d_in[13];
    const float* b1    = (const float*)d_in[14];
    const float* W2    = (const float*)d_in[15];
    const float* b2    = (const float*)d_in[16];
    float* out = (float*)d_out;

    char* ws = (char*)d_ws;
    const size_t MB = 1024 * 1024;
    const size_t KB = 1024;
    unsigned short* x_hi     = (unsigned short*)(ws);                      // 2 MiB
    unsigned short* x_lo     = (unsigned short*)(ws + 2 * MB);             // 2 MiB
    unsigned short* Weff_hi  = (unsigned short*)(ws + 4 * MB);             // 128 KiB
    unsigned short* Weff_lo  = (unsigned short*)(ws + 4 * MB + 128 * KB);  // 128 KiB
    unsigned short* WinT_hi  = (unsigned short*)(ws + 4 * MB + 256 * KB);  // 32 KiB
    unsigned short* WinT_lo  = (unsigned short*)(ws + 4 * MB + 288 * KB);  // 32 KiB
    unsigned short* WBe_hi   = (unsigned short*)(ws + 4 * MB + 320 * KB);  // 4 KiB
    unsigned short* WBe_lo   = (unsigned short*)(ws + 4 * MB + 324 * KB);  // 4 KiB
    float*          bias_eff = (float*)(ws + 4 * MB + 328 * KB);           // 4 KiB
    float*          bbias    = (float*)(ws + 4 * MB + 332 * KB);           // 128 B
    float*          part     = (float*)(ws + 5 * MB);                      // 4 MiB (S,B,NCH,D,N)
    float*          csum     = (float*)(ws + 9 * MB);                      // 256 KiB

    hipLaunchKernelGGL(k_prep, dim3(XBLK_ + 328), dim3(256), 0, stream,
                       x, Win, bin, Wd, bd, Wtau, WB,
                       x_hi, x_lo, Weff_hi, Weff_lo, bias_eff,
                       WinT_hi, WinT_lo, WBe_hi, WBe_lo, bbias);
    hipLaunchKernelGGL(k_fused_scan, dim3((D_ / 16) * NCH_, B_, S_), dim3(256), 0, stream,
                       x_hi, x_lo, Weff_hi, Weff_lo, WinT_hi, WinT_lo, WBe_hi, WBe_lo,
                       bias_eff, bin, bbias, A_log, part, csum);
    hipLaunchKernelGGL(k_final, dim3(B_), dim3(256), 0, stream,
                       x, Win, bin, part, csum, A_log, WC, Dp, Wout,
                       ln_g, ln_b, W1, b1, W2, b2, out);
}

// Round 9
// 164.697 us; speedup vs baseline: 1.1410x; 1.1410x over previous
//
#include <hip/hip_runtime.h>
#include <hip/hip_bf16.h>
#include <math.h>

#define B_   16
#define L_   1024
#define F_   64
#define D_   256
#define S_   2
#define N_   16
#define H_   32
#define EPS_ 1e-5f
#define BL_  (B_*L_)
#define NCH_ 8          // t-chunks for the parallel scan
#define TC_  (L_/NCH_)  // 128 timesteps per chunk
#define SUB_ 64         // timesteps per sub-chunk
#define TSTR_ 68        // scan tile stride (floats); 272B rows, 16B aligned
#define LOG2E_ 1.44269504088896340736f
#define XBLK_ (BL_*F_/1024)   // 1024 xsplit blocks

typedef __attribute__((ext_vector_type(8))) short  bf16x8;
typedef __attribute__((ext_vector_type(4))) float  f32x4;
typedef __attribute__((ext_vector_type(2))) float  f32x2;

typedef const __attribute__((address_space(1))) void* gas_ptr;
typedef __attribute__((address_space(3))) void*       las_ptr;

#if defined(__has_builtin)
# if __has_builtin(__builtin_amdgcn_exp2f)
#  define EXP2(x) __builtin_amdgcn_exp2f(x)
#  define ASCALE_ LOG2E_
# endif
#endif
#ifndef EXP2
# define EXP2(x) __expf(x)
# define ASCALE_ 1.0f
#endif

__device__ inline void async_copy16(const void* g, void* l) {
    __builtin_amdgcn_global_load_lds((gas_ptr)g, (las_ptr)l, 16, 0, 0);
}

__device__ inline unsigned short f2bf_rne(float x) {
    union { float f; unsigned u; } v; v.f = x;
    unsigned r = v.u + 0x7fff + ((v.u >> 16) & 1);
    return (unsigned short)(r >> 16);
}
__device__ inline float bf2f(unsigned short h) {
    union { float f; unsigned u; } v; v.u = ((unsigned)h) << 16;
    return v.f;
}

// ---------------------------------------------------------------------------
// Kernel 1: combined prep (xsplit + all weight prep).
// ---------------------------------------------------------------------------
__global__ __launch_bounds__(256) void k_prep(const float* __restrict__ x,
                                              const float* __restrict__ Win,
                                              const float* __restrict__ bin,
                                              const float* __restrict__ Wd,
                                              const float* __restrict__ bd,
                                              const float* __restrict__ Wt,
                                              const float* __restrict__ WB,
                                              unsigned short* __restrict__ x_hi,
                                              unsigned short* __restrict__ x_lo,
                                              unsigned short* __restrict__ Weff_hi,
                                              unsigned short* __restrict__ Weff_lo,
                                              float* __restrict__ bias_eff,
                                              unsigned short* __restrict__ WinT_hi,
                                              unsigned short* __restrict__ WinT_lo,
                                              unsigned short* __restrict__ WBe_hi,
                                              unsigned short* __restrict__ WBe_lo,
                                              float* __restrict__ bbias)
{
    const int blk = blockIdx.x;
    const int tid = threadIdx.x;

    if (blk < XBLK_) {
        const int i = (blk * 256 + tid) * 4;
        float4 v = *(const float4*)(x + i);
        ushort4 h4, l4;
        unsigned short hh;
        hh = f2bf_rne(v.x); h4.x = hh; l4.x = f2bf_rne(v.x - bf2f(hh));
        hh = f2bf_rne(v.y); h4.y = hh; l4.y = f2bf_rne(v.y - bf2f(hh));
        hh = f2bf_rne(v.z); h4.z = hh; l4.z = f2bf_rne(v.z - bf2f(hh));
        hh = f2bf_rne(v.w); h4.w = hh; l4.w = f2bf_rne(v.w - bf2f(hh));
        *(ushort4*)(x_hi + i) = h4;
        *(ushort4*)(x_lo + i) = l4;
        return;
    }

    const int job4 = blk - XBLK_;
    const int j    = tid >> 6;          // sub-job 0..3
    const int f    = tid & 63;
    const int job  = job4 * 4 + j;

    __shared__ float col[4][D_];

    if (job < 1024) {                   // Weff: s = job>>9, n = job&511
        const int s = job >> 9, n = job & 511;
        const float* W = (n < 256) ? (Wd + (size_t)s * D_ * D_) : (Wt + (size_t)s * D_ * D_);
        const int e = n & 255;
        for (int d = f; d < D_; d += 64) col[j][d] = W[(size_t)d * D_ + e];
        __syncthreads();
        float a = 0.f;
        for (int d = 0; d < D_; ++d) a += Win[(size_t)f * D_ + d] * col[j][d];
        unsigned short hi = f2bf_rne(a);
        size_t o = ((size_t)s * 512 + n) * F_ + f;
        Weff_hi[o] = hi;
        Weff_lo[o] = f2bf_rne(a - bf2f(hi));
        if (f == 0) {
            float bb = 0.f;
            for (int d = 0; d < D_; ++d) bb += bin[d] * col[j][d];
            if (n < 256) bb += bd[s * D_ + e];
            bias_eff[s * 512 + n] = bb;
        }
    } else if (job < 1024 + D_) {       // WinT
        const int d = job - 1024;
        float v = Win[(size_t)f * D_ + d];
        unsigned short hi = f2bf_rne(v);
        size_t o = (size_t)d * F_ + f;
        WinT_hi[o] = hi;
        WinT_lo[o] = f2bf_rne(v - bf2f(hi));
    } else {                            // WBe
        const int idx = job - (1024 + D_);
        const int s = idx >> 4, n = idx & 15;
        const float* wb = WB + (size_t)s * D_ * N_;
        float a = 0.f;
        for (int d = 0; d < D_; ++d) a += Win[(size_t)f * D_ + d] * wb[(size_t)d * N_ + n];
        unsigned short hi = f2bf_rne(a);
        size_t o = ((size_t)s * N_ + n) * F_ + f;
        WBe_hi[o] = hi;
        WBe_lo[o] = f2bf_rne(a - bf2f(hi));
        if (f == 0) {
            float bb = 0.f;
            for (int d = 0; d < D_; ++d) bb += bin[d] * wb[(size_t)d * N_ + n];
            bbias[s * N_ + n] = bb;
        }
    }
}

// ---------------------------------------------------------------------------
// Kernel 2: FUSED gemm + activation + scan (unchanged from round 7/8 shape).
// ---------------------------------------------------------------------------
__global__ __launch_bounds__(256) void k_fused_scan(
        const unsigned short* __restrict__ x_hi,
        const unsigned short* __restrict__ x_lo,
        const unsigned short* __restrict__ Weff_hi,
        const unsigned short* __restrict__ Weff_lo,
        const unsigned short* __restrict__ WinT_hi,
        const unsigned short* __restrict__ WinT_lo,
        const unsigned short* __restrict__ WBe_hi,
        const unsigned short* __restrict__ WBe_lo,
        const float* __restrict__ bias_eff,
        const float* __restrict__ bin,
        const float* __restrict__ bbias,
        const float* __restrict__ A_log,
        float* __restrict__ part,
        float* __restrict__ csum)
{
    const int dtile = blockIdx.x >> 3;
    const int c     = blockIdx.x & 7;
    const int b     = blockIdx.y;
    const int s     = blockIdx.z;
    const int d0    = dtile * 16;
    const int tid   = threadIdx.x;
    const int wid   = tid >> 6;
    const int lane  = tid & 63;
    const int l15   = lane & 15;
    const int quad  = lane >> 4;
    const int dl    = tid & 15;
    const int nl    = tid >> 4;

    __shared__ unsigned short Wh[64 * F_];
    __shared__ unsigned short Wl[64 * F_];
    __shared__ float sdl[16][TSTR_];
    __shared__ float sq [16][TSTR_];
    __shared__ float sb [16][TSTR_];

    const int r8 = lane >> 3;
    const int c8 = lane & 7;

    #pragma unroll
    for (int call = 0; call < 2; ++call) {
        const int rr = call * 8 + r8;
        const int ar = wid * 16 + rr;
        const int lc = (c8 - ar) & 7;
        const unsigned short *gh, *gl;
        if (wid == 0)      { size_t o = ((size_t)s * 512 + d0 + rr) * F_ + lc * 8;       gh = Weff_hi + o; gl = Weff_lo + o; }
        else if (wid == 1) { size_t o = ((size_t)s * 512 + 256 + d0 + rr) * F_ + lc * 8; gh = Weff_hi + o; gl = Weff_lo + o; }
        else if (wid == 2) { size_t o = ((size_t)(d0 + rr)) * F_ + lc * 8;               gh = WinT_hi + o; gl = WinT_lo + o; }
        else               { size_t o = ((size_t)s * N_ + rr) * F_ + lc * 8;             gh = WBe_hi + o;  gl = WBe_lo + o; }
        async_copy16(gh, &Wh[(wid * 16 + call * 8) * F_]);
        async_copy16(gl, &Wl[(wid * 16 + call * 8) * F_]);
    }

    const float bias_d = bias_eff[s * 512 + d0 + l15];
    const float bias_t = bias_eff[s * 512 + 256 + d0 + l15];
    const float bin_v  = bin[d0 + l15];
    const float bb_v   = bbias[s * N_ + l15];
    const float A2 = -__expf(A_log[((size_t)s * D_ + d0 + dl) * N_ + nl]) * ASCALE_;

    f32x2 st01 = {0.f, 0.f};
    f32x2 st23 = {0.f, 0.f};
    float As = 0.f;

    const int qoff = quad * 8;
    const int nsc  = TC_ / SUB_;

    bf16x8 fah0, fah1, fal0, fal1;
    {
        const size_t rowb = ((size_t)b * L_ + c * TC_ + (nsc - 1) * SUB_ + wid * 16 + l15) * F_;
        fah0 = *(const bf16x8*)(x_hi + rowb + qoff);
        fah1 = *(const bf16x8*)(x_hi + rowb + 32 + qoff);
        fal0 = *(const bf16x8*)(x_lo + rowb + qoff);
        fal1 = *(const bf16x8*)(x_lo + rowb + 32 + qoff);
    }
    __syncthreads();

    for (int sc = nsc - 1; sc >= 0; --sc) {
        f32x4 acc[4];
        #pragma unroll
        for (int g = 0; g < 4; ++g) acc[g] = (f32x4){0.f, 0.f, 0.f, 0.f};
        #pragma unroll
        for (int ks = 0; ks < 2; ++ks) {
            bf16x8 ah = ks ? fah1 : fah0;
            bf16x8 al = ks ? fal1 : fal0;
            #pragma unroll
            for (int g = 0; g < 4; ++g) {
                const int brow = g * 16 + l15;
                const int pcB  = ((ks * 4 + quad) + brow) & 7;
                bf16x8 bh = *(const bf16x8*)&Wh[brow * F_ + pcB * 8];
                bf16x8 bl = *(const bf16x8*)&Wl[brow * F_ + pcB * 8];
                acc[g] = __builtin_amdgcn_mfma_f32_16x16x32_bf16(ah, bh, acc[g], 0, 0, 0);
                acc[g] = __builtin_amdgcn_mfma_f32_16x16x32_bf16(ah, bl, acc[g], 0, 0, 0);
                acc[g] = __builtin_amdgcn_mfma_f32_16x16x32_bf16(al, bh, acc[g], 0, 0, 0);
            }
        }

        bf16x8 nah0, nah1, nal0, nal1;
        const bool more = (sc > 0);
        if (more) {
            const size_t rowb = ((size_t)b * L_ + c * TC_ + (sc - 1) * SUB_ + wid * 16 + l15) * F_;
            nah0 = *(const bf16x8*)(x_hi + rowb + qoff);
            nah1 = *(const bf16x8*)(x_hi + rowb + 32 + qoff);
            nal0 = *(const bf16x8*)(x_lo + rowb + qoff);
            nal1 = *(const bf16x8*)(x_lo + rowb + 32 + qoff);
        }

        __syncthreads();

        {
            f32x4 wd_, wq_, wb_;
            #pragma unroll
            for (int r = 0; r < 4; ++r) {
                const float pd  = acc[0][r] + bias_d;
                const float sp  = fmaxf(pd, 0.f) + __logf(1.f + __expf(-fabsf(pd)));
                const float sg  = 1.f / (1.f + __expf(-(acc[1][r] + bias_t)));
                const float dlt = sp * sg;
                const float hv  = acc[2][r] + bin_v;
                wd_[r] = dlt;
                wq_[r] = dlt * hv;
                wb_[r] = acc[3][r] + bb_v;
            }
            const int tcol = wid * 16 + quad * 4;
            *(f32x4*)&sdl[l15][tcol] = wd_;
            *(f32x4*)&sq [l15][tcol] = wq_;
            *(f32x4*)&sb [l15][tcol] = wb_;
        }
        __syncthreads();

        #pragma unroll 4
        for (int tt = SUB_ - 4; tt >= 0; tt -= 4) {
            f32x4 dp = *(const f32x4*)&sdl[dl][tt];
            f32x4 qp = *(const f32x4*)&sq [dl][tt];
            f32x4 bp = *(const f32x4*)&sb [nl][tt];
            const float a2v = fmaf(A2, dp.w, As);
            const float a1v = fmaf(A2, dp.z, a2v);
            const float a0v = fmaf(A2, dp.y, a1v);
            f32x2 e01, e23;
            e23.y = EXP2(As);
            e23.x = EXP2(a2v);
            e01.y = EXP2(a1v);
            e01.x = EXP2(a0v);
            f32x2 q01 = {qp.x, qp.y}, q23 = {qp.z, qp.w};
            f32x2 b01 = {bp.x, bp.y}, b23 = {bp.z, bp.w};
            st01 = q01 * b01 * e01 + st01;
            st23 = q23 * b23 * e23 + st23;
            As = fmaf(A2, dp.x, a0v);
        }

        if (more) { fah0 = nah0; fah1 = nah1; fal0 = nal0; fal1 = nal1; }
    }

    const size_t pb = ((size_t)s * B_ + b) * NCH_ + c;
    part[(pb * D_ + d0 + dl) * N_ + nl] = (st01.x + st01.y) + (st23.x + st23.y);
    if (nl == 0)
        csum[pb * D_ + d0 + dl] = As / A2;
}

// ---------------------------------------------------------------------------
// Kernel 3a: ys[s][b][d] = sum_n cm[s,b,n]*state[d,n] + h_last[d]*Dp.
// Grid (S_, B_) = 32 blocks x 256 thr (tid = d). Inline chunk-combine.
// ---------------------------------------------------------------------------
__global__ __launch_bounds__(256) void k_ys(const float* __restrict__ x,
                                            const float* __restrict__ Win,
                                            const float* __restrict__ bin,
                                            const float* __restrict__ part,
                                            const float* __restrict__ csum,
                                            const float* __restrict__ A_log,
                                            const float* __restrict__ WC,
                                            const float* __restrict__ Dp,
                                            float* __restrict__ ys)
{
    const int s   = blockIdx.x;
    const int b   = blockIdx.y;
    const int tid = threadIdx.x;

    __shared__ float xr[F_];
    __shared__ float hl[D_];
    __shared__ float cm[N_];
    __shared__ float cred[N_][17];

    if (tid < F_) xr[tid] = x[((size_t)b * L_ + (L_ - 1)) * F_ + tid];
    __syncthreads();

    {   // h_last[d]
        float a = bin[tid];
        for (int f = 0; f < F_; ++f) a += xr[f] * Win[(size_t)f * D_ + tid];
        hl[tid] = a;
    }
    __syncthreads();

    {   // cm[n] = sum_d hl[d] * WC[s][d][n]; parallel partial over 16 d-slices
        const int n  = tid & 15;
        const int dq = tid >> 4;       // 16 slices of 16 d
        float a = 0.f;
        for (int d = dq * 16; d < dq * 16 + 16; ++d)
            a += hl[d] * WC[((size_t)s * D_ + d) * N_ + n];
        cred[n][dq] = a;
    }
    __syncthreads();
    if (tid < N_) {
        float a = 0.f;
        #pragma unroll
        for (int q = 0; q < 16; ++q) a += cred[tid][q];
        cm[tid] = a;
    }
    __syncthreads();

    // per-thread (d = tid) combine across chunks
    const float* al = A_log + ((size_t)s * D_ + tid) * N_;
    float a2v[N_];
    #pragma unroll
    for (int n = 0; n < N_; ++n) a2v[n] = -__expf(al[n]);
    const size_t cbase = ((size_t)s * B_ + b) * NCH_;
    float acc = 0.f;
    float tail = 0.f;
    for (int c = NCH_ - 1; c >= 0; --c) {
        const float* pp = part + ((cbase + c) * D_ + tid) * N_;
        #pragma unroll
        for (int n = 0; n < N_; ++n)
            acc += cm[n] * __expf(a2v[n] * tail) * pp[n];
        tail += csum[(cbase + c) * D_ + tid];
    }
    ys[((size_t)s * B_ + b) * D_ + tid] = acc + hl[tid] * Dp[s * D_ + tid];
}

// ---------------------------------------------------------------------------
// Kernel 3b: last[b][e] = (1/S) sum_{s,d} ys[s][b][d] * Wout[s][d][e].
// Grid (B_, 4 e-tiles) = 64 blocks; 4-way split-K over waves.
// ---------------------------------------------------------------------------
__global__ __launch_bounds__(256) void k_last(const float* __restrict__ ys,
                                              const float* __restrict__ Wout,
                                              float* __restrict__ last)
{
    const int b  = blockIdx.x;
    const int e0 = blockIdx.y * 64;
    const int tid = threadIdx.x;
    const int e  = tid & 63;
    const int kq = tid >> 6;

    __shared__ float ysl[S_ * D_];
    __shared__ float red[4][64];

    #pragma unroll
    for (int j = tid; j < S_ * D_; j += 256) {
        const int ss = j >> 8, dd = j & 255;
        ysl[j] = ys[((size_t)ss * B_ + b) * D_ + dd];
    }
    __syncthreads();

    float a = 0.f;
    for (int k = kq * 128; k < kq * 128 + 128; ++k) {
        const int ss = k >> 8, dd = k & 255;
        a += ysl[k] * Wout[((size_t)ss * D_ + dd) * D_ + e0 + e];
    }
    red[kq][e] = a;
    __syncthreads();
    if (kq == 0) {
        const float v = (red[0][e] + red[1][e] + red[2][e] + red[3][e]) * (1.f / S_);
        last[(size_t)b * D_ + e0 + e] = v;
    }
}

// ---------------------------------------------------------------------------
// Kernel 3c: LayerNorm + MLP head. Grid B_ blocks.
// ---------------------------------------------------------------------------
__global__ __launch_bounds__(256) void k_head(const float* __restrict__ last,
                                              const float* __restrict__ ln_g,
                                              const float* __restrict__ ln_b,
                                              const float* __restrict__ W1,
                                              const float* __restrict__ b1,
                                              const float* __restrict__ W2,
                                              const float* __restrict__ b2,
                                              float* __restrict__ out)
{
    const int b   = blockIdx.x;
    const int tid = threadIdx.x;

    __shared__ float zv[D_];
    __shared__ float red1[256];
    __shared__ float red2[256];
    __shared__ float r1[H_];

    const float v = last[(size_t)b * D_ + tid];
    red1[tid] = v;
    red2[tid] = v * v;
    __syncthreads();
    for (int off = 128; off > 0; off >>= 1) {
        if (tid < off) { red1[tid] += red1[tid + off]; red2[tid] += red2[tid + off]; }
        __syncthreads();
    }
    const float mu  = red1[0] * (1.f / D_);
    const float var = red2[0] * (1.f / D_) - mu * mu;
    const float z = (v - mu) * rsqrtf(var + EPS_) * ln_g[tid] + ln_b[tid];
    zv[tid] = z;
    __syncthreads();

    if (tid < H_) {
        float a = b1[tid];
        for (int e = 0; e < D_; ++e) a += zv[e] * W1[(size_t)e * H_ + tid];
        r1[tid] = fmaxf(a, 0.f);
    }
    __syncthreads();
    if (tid == 0) {
        float a = b2[0];
        for (int j = 0; j < H_; ++j) a += r1[j] * W2[j];
        out[b] = a;
    }
}

// ---------------------------------------------------------------------------
extern "C" void kernel_launch(void* const* d_in, const int* in_sizes, int n_in,
                              void* d_out, int out_size, void* d_ws, size_t ws_size,
                              hipStream_t stream)
{
    const float* x     = (const float*)d_in[0];
    const float* Win   = (const float*)d_in[1];
    const float* bin   = (const float*)d_in[2];
    const float* Wd    = (const float*)d_in[3];
    const float* bd    = (const float*)d_in[4];
    const float* WB    = (const float*)d_in[5];
    const float* WC    = (const float*)d_in[6];
    const float* Wtau  = (const float*)d_in[7];
    const float* A_log = (const float*)d_in[8];
    const float* Dp    = (const float*)d_in[9];
    const float* Wout  = (const float*)d_in[10];
    const float* ln_g  = (const float*)d_in[11];
    const float* ln_b  = (const float*)d_in[12];
    const float* W1    = (const float*)d_in[13];
    const float* b1    = (const float*)d_in[14];
    const float* W2    = (const float*)d_in[15];
    const float* b2    = (const float*)d_in[16];
    float* out = (float*)d_out;

    char* ws = (char*)d_ws;
    const size_t MB = 1024 * 1024;
    const size_t KB = 1024;
    unsigned short* x_hi     = (unsigned short*)(ws);                      // 2 MiB
    unsigned short* x_lo     = (unsigned short*)(ws + 2 * MB);             // 2 MiB
    unsigned short* Weff_hi  = (unsigned short*)(ws + 4 * MB);             // 128 KiB
    unsigned short* Weff_lo  = (unsigned short*)(ws + 4 * MB + 128 * KB);  // 128 KiB
    unsigned short* WinT_hi  = (unsigned short*)(ws + 4 * MB + 256 * KB);  // 32 KiB
    unsigned short* WinT_lo  = (unsigned short*)(ws + 4 * MB + 288 * KB);  // 32 KiB
    unsigned short* WBe_hi   = (unsigned short*)(ws + 4 * MB + 320 * KB);  // 4 KiB
    unsigned short* WBe_lo   = (unsigned short*)(ws + 4 * MB + 324 * KB);  // 4 KiB
    float*          bias_eff = (float*)(ws + 4 * MB + 328 * KB);           // 4 KiB
    float*          bbias    = (float*)(ws + 4 * MB + 332 * KB);           // 128 B
    float*          part     = (float*)(ws + 5 * MB);                      // 4 MiB
    float*          csum     = (float*)(ws + 9 * MB);                      // 256 KiB
    float*          ysbuf    = (float*)(ws + 9 * MB + 256 * KB);           // 32 KiB
    float*          lastbuf  = (float*)(ws + 9 * MB + 512 * KB);           // 16 KiB

    hipLaunchKernelGGL(k_prep, dim3(XBLK_ + 328), dim3(256), 0, stream,
                       x, Win, bin, Wd, bd, Wtau, WB,
                       x_hi, x_lo, Weff_hi, Weff_lo, bias_eff,
                       WinT_hi, WinT_lo, WBe_hi, WBe_lo, bbias);
    hipLaunchKernelGGL(k_fused_scan, dim3((D_ / 16) * NCH_, B_, S_), dim3(256), 0, stream,
                       x_hi, x_lo, Weff_hi, Weff_lo, WinT_hi, WinT_lo, WBe_hi, WBe_lo,
                       bias_eff, bin, bbias, A_log, part, csum);
    hipLaunchKernelGGL(k_ys,   dim3(S_, B_), dim3(256), 0, stream,
                       x, Win, bin, part, csum, A_log, WC, Dp, ysbuf);
    hipLaunchKernelGGL(k_last, dim3(B_, 4), dim3(256), 0, stream, ysbuf, Wout, lastbuf);
    hipLaunchKernelGGL(k_head, dim3(B_), dim3(256), 0, stream,
                       lastbuf, ln_g, ln_b, W1, b1, W2, b2, out);
}

// Round 10
// 162.094 us; speedup vs baseline: 1.1594x; 1.0161x over previous
//
#include <hip/hip_runtime.h>
#include <hip/hip_bf16.h>
#include <math.h>

#define B_   16
#define L_   1024
#define F_   64
#define D_   256
#define S_   2
#define N_   16
#define H_   32
#define EPS_ 1e-5f
#define BL_  (B_*L_)
#define NCH_ 8          // t-chunks for the parallel scan
#define TC_  (L_/NCH_)  // 128 timesteps per chunk
#define SUB_ 64         // timesteps per sub-chunk
#define TSTR_ 68        // scan tile stride (floats); 272B rows, 16B aligned
#define LOG2E_ 1.44269504088896340736f
#define XBLK_ (BL_*F_/1024)   // 1024 xsplit blocks

typedef __attribute__((ext_vector_type(8))) short  bf16x8;
typedef __attribute__((ext_vector_type(4))) float  f32x4;
typedef __attribute__((ext_vector_type(2))) float  f32x2;

typedef const __attribute__((address_space(1))) void* gas_ptr;
typedef __attribute__((address_space(3))) void*       las_ptr;

#if defined(__has_builtin)
# if __has_builtin(__builtin_amdgcn_exp2f)
#  define EXP2(x) __builtin_amdgcn_exp2f(x)
#  define ASCALE_ LOG2E_
# endif
#endif
#ifndef EXP2
# define EXP2(x) __expf(x)
# define ASCALE_ 1.0f
#endif

__device__ inline void async_copy16(const void* g, void* l) {
    __builtin_amdgcn_global_load_lds((gas_ptr)g, (las_ptr)l, 16, 0, 0);
}

__device__ inline unsigned short f2bf_rne(float x) {
    union { float f; unsigned u; } v; v.f = x;
    unsigned r = v.u + 0x7fff + ((v.u >> 16) & 1);
    return (unsigned short)(r >> 16);
}

// ---------------------------------------------------------------------------
// Kernel 1: combined prep (x -> bf16, composed weights -> bf16).
//  blocks [0, XBLK_):      x_hi = bf16(x)
//  blocks [XBLK_, +256):   Weff cols (4 jobs x 64 thr) + biases
//  blocks [+256, +64):     WinT rows (4 jobs)
//  blocks [+320, +8):      WBe cols (4 jobs) + bbias
// ---------------------------------------------------------------------------
__global__ __launch_bounds__(256) void k_prep(const float* __restrict__ x,
                                              const float* __restrict__ Win,
                                              const float* __restrict__ bin,
                                              const float* __restrict__ Wd,
                                              const float* __restrict__ bd,
                                              const float* __restrict__ Wt,
                                              const float* __restrict__ WB,
                                              unsigned short* __restrict__ x_hi,
                                              unsigned short* __restrict__ Weff_hi,
                                              float* __restrict__ bias_eff,
                                              unsigned short* __restrict__ WinT_hi,
                                              unsigned short* __restrict__ WBe_hi,
                                              float* __restrict__ bbias)
{
    const int blk = blockIdx.x;
    const int tid = threadIdx.x;

    if (blk < XBLK_) {
        const int i = (blk * 256 + tid) * 4;
        float4 v = *(const float4*)(x + i);
        ushort4 h4;
        h4.x = f2bf_rne(v.x);
        h4.y = f2bf_rne(v.y);
        h4.z = f2bf_rne(v.z);
        h4.w = f2bf_rne(v.w);
        *(ushort4*)(x_hi + i) = h4;
        return;
    }

    const int job4 = blk - XBLK_;
    const int j    = tid >> 6;          // sub-job 0..3
    const int f    = tid & 63;
    const int job  = job4 * 4 + j;

    __shared__ float col[4][D_];

    if (job < 1024) {                   // Weff: s = job>>9, n = job&511
        const int s = job >> 9, n = job & 511;
        const float* W = (n < 256) ? (Wd + (size_t)s * D_ * D_) : (Wt + (size_t)s * D_ * D_);
        const int e = n & 255;
        for (int d = f; d < D_; d += 64) col[j][d] = W[(size_t)d * D_ + e];
        __syncthreads();
        float a = 0.f;
        for (int d = 0; d < D_; ++d) a += Win[(size_t)f * D_ + d] * col[j][d];
        Weff_hi[((size_t)s * 512 + n) * F_ + f] = f2bf_rne(a);
        if (f == 0) {
            float bb = 0.f;
            for (int d = 0; d < D_; ++d) bb += bin[d] * col[j][d];
            if (n < 256) bb += bd[s * D_ + e];
            bias_eff[s * 512 + n] = bb;
        }
    } else if (job < 1024 + D_) {       // WinT
        const int d = job - 1024;
        WinT_hi[(size_t)d * F_ + f] = f2bf_rne(Win[(size_t)f * D_ + d]);
    } else {                            // WBe
        const int idx = job - (1024 + D_);
        const int s = idx >> 4, n = idx & 15;
        const float* wb = WB + (size_t)s * D_ * N_;
        float a = 0.f;
        for (int d = 0; d < D_; ++d) a += Win[(size_t)f * D_ + d] * wb[(size_t)d * N_ + n];
        WBe_hi[((size_t)s * N_ + n) * F_ + f] = f2bf_rne(a);
        if (f == 0) {
            float bb = 0.f;
            for (int d = 0; d < D_; ++d) bb += bin[d] * wb[(size_t)d * N_ + n];
            bbias[s * N_ + n] = bb;
        }
    }
}

// ---------------------------------------------------------------------------
// Kernel 2: FUSED gemm + activation + scan, bf16-only GEMM.
// One block per (s, b, d-tile, t-chunk of 128). A-fragments direct
// global->VGPR (prefetched); W strip (8 KB) in LDS. Scan: 4 t/iter, b128
// tile reads, raw v_exp (log2 domain), packed f32 accumulators.
// ---------------------------------------------------------------------------
__global__ __launch_bounds__(256) void k_fused_scan(
        const unsigned short* __restrict__ x_hi,
        const unsigned short* __restrict__ Weff_hi,
        const unsigned short* __restrict__ WinT_hi,
        const unsigned short* __restrict__ WBe_hi,
        const float* __restrict__ bias_eff,
        const float* __restrict__ bin,
        const float* __restrict__ bbias,
        const float* __restrict__ A_log,
        float* __restrict__ part,
        float* __restrict__ csum)
{
    const int dtile = blockIdx.x >> 3;
    const int c     = blockIdx.x & 7;
    const int b     = blockIdx.y;
    const int s     = blockIdx.z;
    const int d0    = dtile * 16;
    const int tid   = threadIdx.x;
    const int wid   = tid >> 6;
    const int lane  = tid & 63;
    const int l15   = lane & 15;
    const int quad  = lane >> 4;
    const int dl    = tid & 15;
    const int nl    = tid >> 4;

    __shared__ unsigned short Wh[64 * F_];  // [col][f]: 0-15 d,16-31 tau,32-47 Win,48-63 WB
    __shared__ float sdl[16][TSTR_];        // [d][t] delta
    __shared__ float sq [16][TSTR_];        // [d][t] delta*h
    __shared__ float sb [16][TSTR_];        // [n][t] Bm

    const int r8 = lane >> 3;
    const int c8 = lane & 7;

    // ---- stage W strip once (wave wid = col group wid)
    #pragma unroll
    for (int call = 0; call < 2; ++call) {
        const int rr = call * 8 + r8;
        const int ar = wid * 16 + rr;
        const int lc = (c8 - ar) & 7;
        const unsigned short* gh;
        if (wid == 0)      gh = Weff_hi + ((size_t)s * 512 + d0 + rr) * F_ + lc * 8;
        else if (wid == 1) gh = Weff_hi + ((size_t)s * 512 + 256 + d0 + rr) * F_ + lc * 8;
        else if (wid == 2) gh = WinT_hi + ((size_t)(d0 + rr)) * F_ + lc * 8;
        else               gh = WBe_hi + ((size_t)s * N_ + rr) * F_ + lc * 8;
        async_copy16(gh, &Wh[(wid * 16 + call * 8) * F_]);
    }

    const float bias_d = bias_eff[s * 512 + d0 + l15];
    const float bias_t = bias_eff[s * 512 + 256 + d0 + l15];
    const float bin_v  = bin[d0 + l15];
    const float bb_v   = bbias[s * N_ + l15];
    const float A2 = -__expf(A_log[((size_t)s * D_ + d0 + dl) * N_ + nl]) * ASCALE_;

    f32x2 st01 = {0.f, 0.f};
    f32x2 st23 = {0.f, 0.f};
    float As = 0.f;

    const int qoff = quad * 8;
    const int nsc  = TC_ / SUB_;

    bf16x8 fah0, fah1;
    {
        const size_t rowb = ((size_t)b * L_ + c * TC_ + (nsc - 1) * SUB_ + wid * 16 + l15) * F_;
        fah0 = *(const bf16x8*)(x_hi + rowb + qoff);
        fah1 = *(const bf16x8*)(x_hi + rowb + 32 + qoff);
    }
    __syncthreads();   // W staged

    for (int sc = nsc - 1; sc >= 0; --sc) {
        // ---- MFMA: this wave's 16 t-rows x 4 col groups, K=64, bf16-only
        f32x4 acc[4];
        #pragma unroll
        for (int g = 0; g < 4; ++g) acc[g] = (f32x4){0.f, 0.f, 0.f, 0.f};
        #pragma unroll
        for (int ks = 0; ks < 2; ++ks) {
            bf16x8 ah = ks ? fah1 : fah0;
            #pragma unroll
            for (int g = 0; g < 4; ++g) {
                const int brow = g * 16 + l15;
                const int pcB  = ((ks * 4 + quad) + brow) & 7;
                bf16x8 bh = *(const bf16x8*)&Wh[brow * F_ + pcB * 8];
                acc[g] = __builtin_amdgcn_mfma_f32_16x16x32_bf16(ah, bh, acc[g], 0, 0, 0);
            }
        }

        // ---- prefetch next sub-chunk's A-fragments (completes under scan)
        bf16x8 nah0, nah1;
        const bool more = (sc > 0);
        if (more) {
            const size_t rowb = ((size_t)b * L_ + c * TC_ + (sc - 1) * SUB_ + wid * 16 + l15) * F_;
            nah0 = *(const bf16x8*)(x_hi + rowb + qoff);
            nah1 = *(const bf16x8*)(x_hi + rowb + 32 + qoff);
        }

        __syncthreads();   // previous scan reads done before tile overwrite

        // ---- epilogue: C layout col=l15, row=quad*4+r -> transposed tiles
        {
            f32x4 wd_, wq_, wb_;
            #pragma unroll
            for (int r = 0; r < 4; ++r) {
                const float pd  = acc[0][r] + bias_d;
                const float sp  = fmaxf(pd, 0.f) + __logf(1.f + __expf(-fabsf(pd)));
                const float sg  = 1.f / (1.f + __expf(-(acc[1][r] + bias_t)));
                const float dlt = sp * sg;
                const float hv  = acc[2][r] + bin_v;
                wd_[r] = dlt;
                wq_[r] = dlt * hv;
                wb_[r] = acc[3][r] + bb_v;
            }
            const int tcol = wid * 16 + quad * 4;
            *(f32x4*)&sdl[l15][tcol] = wd_;
            *(f32x4*)&sq [l15][tcol] = wq_;
            *(f32x4*)&sb [l15][tcol] = wb_;
        }
        __syncthreads();

        // ---- backward suffix scan, 4 timesteps per iteration
        #pragma unroll 4
        for (int tt = SUB_ - 4; tt >= 0; tt -= 4) {
            f32x4 dp = *(const f32x4*)&sdl[dl][tt];
            f32x4 qp = *(const f32x4*)&sq [dl][tt];
            f32x4 bp = *(const f32x4*)&sb [nl][tt];
            const float a2v = fmaf(A2, dp.w, As);
            const float a1v = fmaf(A2, dp.z, a2v);
            const float a0v = fmaf(A2, dp.y, a1v);
            f32x2 e01, e23;
            e23.y = EXP2(As);
            e23.x = EXP2(a2v);
            e01.y = EXP2(a1v);
            e01.x = EXP2(a0v);
            f32x2 q01 = {qp.x, qp.y}, q23 = {qp.z, qp.w};
            f32x2 b01 = {bp.x, bp.y}, b23 = {bp.z, bp.w};
            st01 = q01 * b01 * e01 + st01;
            st23 = q23 * b23 * e23 + st23;
            As = fmaf(A2, dp.x, a0v);
        }

        if (more) { fah0 = nah0; fah1 = nah1; }
    }

    const size_t pb = ((size_t)s * B_ + b) * NCH_ + c;
    part[(pb * D_ + d0 + dl) * N_ + nl] = (st01.x + st01.y) + (st23.x + st23.y);
    if (nl == 0)
        csum[pb * D_ + d0 + dl] = As / A2;
}

// ---------------------------------------------------------------------------
// Kernel 3a: ys[s][b][d] = sum_n cm[s,b,n]*state[d,n] + h_last[d]*Dp.
// ---------------------------------------------------------------------------
__global__ __launch_bounds__(256) void k_ys(const float* __restrict__ x,
                                            const float* __restrict__ Win,
                                            const float* __restrict__ bin,
                                            const float* __restrict__ part,
                                            const float* __restrict__ csum,
                                            const float* __restrict__ A_log,
                                            const float* __restrict__ WC,
                                            const float* __restrict__ Dp,
                                            float* __restrict__ ys)
{
    const int s   = blockIdx.x;
    const int b   = blockIdx.y;
    const int tid = threadIdx.x;

    __shared__ float xr[F_];
    __shared__ float hl[D_];
    __shared__ float cm[N_];
    __shared__ float cred[N_][17];

    if (tid < F_) xr[tid] = x[((size_t)b * L_ + (L_ - 1)) * F_ + tid];
    __syncthreads();

    {
        float a = bin[tid];
        for (int f = 0; f < F_; ++f) a += xr[f] * Win[(size_t)f * D_ + tid];
        hl[tid] = a;
    }
    __syncthreads();

    {
        const int n  = tid & 15;
        const int dq = tid >> 4;
        float a = 0.f;
        for (int d = dq * 16; d < dq * 16 + 16; ++d)
            a += hl[d] * WC[((size_t)s * D_ + d) * N_ + n];
        cred[n][dq] = a;
    }
    __syncthreads();
    if (tid < N_) {
        float a = 0.f;
        #pragma unroll
        for (int q = 0; q < 16; ++q) a += cred[tid][q];
        cm[tid] = a;
    }
    __syncthreads();

    const float* al = A_log + ((size_t)s * D_ + tid) * N_;
    float a2v[N_];
    #pragma unroll
    for (int n = 0; n < N_; ++n) a2v[n] = -__expf(al[n]);
    const size_t cbase = ((size_t)s * B_ + b) * NCH_;
    float acc = 0.f;
    float tail = 0.f;
    for (int c = NCH_ - 1; c >= 0; --c) {
        const float* pp = part + ((cbase + c) * D_ + tid) * N_;
        #pragma unroll
        for (int n = 0; n < N_; ++n)
            acc += cm[n] * __expf(a2v[n] * tail) * pp[n];
        tail += csum[(cbase + c) * D_ + tid];
    }
    ys[((size_t)s * B_ + b) * D_ + tid] = acc + hl[tid] * Dp[s * D_ + tid];
}

// ---------------------------------------------------------------------------
// Kernel 3b: last[b][e] = (1/S) sum_{s,d} ys[s][b][d] * Wout[s][d][e].
// ---------------------------------------------------------------------------
__global__ __launch_bounds__(256) void k_last(const float* __restrict__ ys,
                                              const float* __restrict__ Wout,
                                              float* __restrict__ last)
{
    const int b  = blockIdx.x;
    const int e0 = blockIdx.y * 64;
    const int tid = threadIdx.x;
    const int e  = tid & 63;
    const int kq = tid >> 6;

    __shared__ float ysl[S_ * D_];
    __shared__ float red[4][64];

    #pragma unroll
    for (int j = tid; j < S_ * D_; j += 256) {
        const int ss = j >> 8, dd = j & 255;
        ysl[j] = ys[((size_t)ss * B_ + b) * D_ + dd];
    }
    __syncthreads();

    float a = 0.f;
    for (int k = kq * 128; k < kq * 128 + 128; ++k) {
        const int ss = k >> 8, dd = k & 255;
        a += ysl[k] * Wout[((size_t)ss * D_ + dd) * D_ + e0 + e];
    }
    red[kq][e] = a;
    __syncthreads();
    if (kq == 0) {
        const float v = (red[0][e] + red[1][e] + red[2][e] + red[3][e]) * (1.f / S_);
        last[(size_t)b * D_ + e0 + e] = v;
    }
}

// ---------------------------------------------------------------------------
// Kernel 3c: LayerNorm + MLP head.
// ---------------------------------------------------------------------------
__global__ __launch_bounds__(256) void k_head(const float* __restrict__ last,
                                              const float* __restrict__ ln_g,
                                              const float* __restrict__ ln_b,
                                              const float* __restrict__ W1,
                                              const float* __restrict__ b1,
                                              const float* __restrict__ W2,
                                              const float* __restrict__ b2,
                                              float* __restrict__ out)
{
    const int b   = blockIdx.x;
    const int tid = threadIdx.x;

    __shared__ float zv[D_];
    __shared__ float red1[256];
    __shared__ float red2[256];
    __shared__ float r1[H_];

    const float v = last[(size_t)b * D_ + tid];
    red1[tid] = v;
    red2[tid] = v * v;
    __syncthreads();
    for (int off = 128; off > 0; off >>= 1) {
        if (tid < off) { red1[tid] += red1[tid + off]; red2[tid] += red2[tid + off]; }
        __syncthreads();
    }
    const float mu  = red1[0] * (1.f / D_);
    const float var = red2[0] * (1.f / D_) - mu * mu;
    const float z = (v - mu) * rsqrtf(var + EPS_) * ln_g[tid] + ln_b[tid];
    zv[tid] = z;
    __syncthreads();

    if (tid < H_) {
        float a = b1[tid];
        for (int e = 0; e < D_; ++e) a += zv[e] * W1[(size_t)e * H_ + tid];
        r1[tid] = fmaxf(a, 0.f);
    }
    __syncthreads();
    if (tid == 0) {
        float a = b2[0];
        for (int j = 0; j < H_; ++j) a += r1[j] * W2[j];
        out[b] = a;
    }
}

// ---------------------------------------------------------------------------
extern "C" void kernel_launch(void* const* d_in, const int* in_sizes, int n_in,
                              void* d_out, int out_size, void* d_ws, size_t ws_size,
                              hipStream_t stream)
{
    const float* x     = (const float*)d_in[0];
    const float* Win   = (const float*)d_in[1];
    const float* bin   = (const float*)d_in[2];
    const float* Wd    = (const float*)d_in[3];
    const float* bd    = (const float*)d_in[4];
    const float* WB    = (const float*)d_in[5];
    const float* WC    = (const float*)d_in[6];
    const float* Wtau  = (const float*)d_in[7];
    const float* A_log = (const float*)d_in[8];
    const float* Dp    = (const float*)d_in[9];
    const float* Wout  = (const float*)d_in[10];
    const float* ln_g  = (const float*)d_in[11];
    const float* ln_b  = (const float*)d_in[12];
    const float* W1    = (const float*)d_in[13];
    const float* b1    = (const float*)d_in[14];
    const float* W2    = (const float*)d_in[15];
    const float* b2    = (const float*)d_in[16];
    float* out = (float*)d_out;

    char* ws = (char*)d_ws;
    const size_t MB = 1024 * 1024;
    const size_t KB = 1024;
    unsigned short* x_hi     = (unsigned short*)(ws);                      // 2 MiB
    unsigned short* Weff_hi  = (unsigned short*)(ws + 2 * MB);             // 128 KiB
    unsigned short* WinT_hi  = (unsigned short*)(ws + 2 * MB + 128 * KB);  // 32 KiB
    unsigned short* WBe_hi   = (unsigned short*)(ws + 2 * MB + 160 * KB);  // 4 KiB
    float*          bias_eff = (float*)(ws + 2 * MB + 164 * KB);           // 4 KiB
    float*          bbias    = (float*)(ws + 2 * MB + 168 * KB);           // 128 B
    float*          part     = (float*)(ws + 3 * MB);                      // 4 MiB
    float*          csum     = (float*)(ws + 7 * MB);                      // 256 KiB
    float*          ysbuf    = (float*)(ws + 7 * MB + 256 * KB);           // 32 KiB
    float*          lastbuf  = (float*)(ws + 7 * MB + 288 * KB);           // 16 KiB

    hipLaunchKernelGGL(k_prep, dim3(XBLK_ + 328), dim3(256), 0, stream,
                       x, Win, bin, Wd, bd, Wtau, WB,
                       x_hi, Weff_hi, bias_eff, WinT_hi, WBe_hi, bbias);
    hipLaunchKernelGGL(k_fused_scan, dim3((D_ / 16) * NCH_, B_, S_), dim3(256), 0, stream,
                       x_hi, Weff_hi, WinT_hi, WBe_hi,
                       bias_eff, bin, bbias, A_log, part, csum);
    hipLaunchKernelGGL(k_ys,   dim3(S_, B_), dim3(256), 0, stream,
                       x, Win, bin, part, csum, A_log, WC, Dp, ysbuf);
    hipLaunchKernelGGL(k_last, dim3(B_, 4), dim3(256), 0, stream, ysbuf, Wout, lastbuf);
    hipLaunchKernelGGL(k_head, dim3(B_), dim3(256), 0, stream,
                       lastbuf, ln_g, ln_b, W1, b1, W2, b2, out);
}